// Round 5
// baseline (480.067 us; speedup 1.0000x reference)
//
#include <hip/hip_runtime.h>
#include <stdint.h>

#define N_ROWS 65536
#define N_CLS  1000
#define KPAD   1024
#define FEAT   256
#define MT     32            // rows per block
#define NSTG   32            // k-stages of 32 (one MFMA k-window each)

typedef short bf16x8 __attribute__((ext_vector_type(8)));
typedef float f32x4  __attribute__((ext_vector_type(4)));

__device__ __forceinline__ ushort f32_to_bf16_rne(float f) {
    union { float f; uint32_t u; } x; x.f = f;
    uint32_t u = x.u + 0x7FFFu + ((x.u >> 16) & 1u);
    return (ushort)(u >> 16);
}

// Prep: store centers as bf16 in EXACT MFMA B-fragment order:
//   Bfrag[s][w][nt][lane][j]  (k = s*32+quad*8+j, lane=quad*16+ml, n=w*64+nt*16+ml)
// so each wave's fragment load in main is ONE coalesced 1 KB dwordx4 burst.
// Also csq[c] = ||centers[c]||^2 (zero-padded to KPAD); zero d_out.
__global__ __launch_bounds__(256) void prep_kernel(const float* __restrict__ centers,
                                                   ushort* __restrict__ Bfrag,
                                                   float* __restrict__ csq,
                                                   float* __restrict__ out) {
    const int c = blockIdx.x;     // k index 0..1023
    const int n = threadIdx.x;    // n index 0..255
    float v = 0.f;
    if (c < N_CLS) v = centers[(size_t)c * FEAT + n];

    const int s    = c >> 5;          // stage = k/32
    const int quad = (c >> 3) & 3;
    const int j    = c & 7;
    const int w    = n >> 6;
    const int nt   = (n >> 4) & 3;
    const int ml   = n & 15;
    const int lane = quad * 16 + ml;
    const size_t idx = (((size_t)(s * 4 + w) * 4 + nt) * 64 + lane) * 8 + j;
    Bfrag[idx] = f32_to_bf16_rne(v);

    float sq = v * v;
    #pragma unroll
    for (int off = 32; off > 0; off >>= 1) sq += __shfl_down(sq, off);
    __shared__ float red[4];
    if ((threadIdx.x & 63) == 0) red[threadIdx.x >> 6] = sq;
    __syncthreads();
    if (threadIdx.x == 0) {
        csq[c] = red[0] + red[1] + red[2] + red[3];
        if (c == 0) out[0] = 0.f;
    }
}

// Barrier-free main loop (no LDS A-tile, no per-iteration __syncthreads):
//  - Each lane loads its OWN gt ints (rows ml, ml+16 of the block; k-chunk
//    quad*8) straight from global and converts to the MFMA A-fragment in
//    registers.  The 4 waves of a block share the same 32 rows -> 4x
//    redundant gt loads, absorbed by L1/L2 (waves free-run in near-lockstep).
//  - B fragments from the L2-resident fragment-ordered table (1 KB bursts).
//  - 2-deep software pipeline, issue-early order so vmcnt waits leave the
//    next stages' loads in flight (gt cover ~1.3 stages, B ~1.7).
//  - gt in {0,1}: pack = (v0 + v1<<16)*0x3F80; integer row-counts; t2 via csq
//    staged once in LDS (broadcast reads).
__global__ __launch_bounds__(256, 3) void main_kernel(const int* __restrict__ gt,
                                                      const float* __restrict__ features,
                                                      const ushort* __restrict__ Bfrag,
                                                      const float* __restrict__ csq,
                                                      float* __restrict__ out) {
    __shared__ float csqS[KPAD];    // 4 KB
    __shared__ float blockred[4];

    const int tid  = threadIdx.x;
    const int lane = tid & 63;
    const int w    = tid >> 6;       // wave 0..3 -> cols w*64
    const int ml   = lane & 15;
    const int quad = lane >> 4;
    const int m0   = blockIdx.x * MT;

    // stage csq -> LDS once
    *(float4*)&csqS[tid * 4] = *(const float4*)&csq[tid * 4];

    f32x4 acc[2][4];
    #pragma unroll
    for (int i = 0; i < 2; i++)
        #pragma unroll
        for (int j = 0; j < 4; j++)
            #pragma unroll
            for (int k = 0; k < 4; k++) acc[i][j][k] = 0.f;

    const int qoff = quad * 8;                               // k offset within a stage
    const int* g0 = gt + (size_t)(m0 + ml) * N_CLS;          // row ml      (mt=0)
    const int* g1 = gt + (size_t)(m0 + 16 + ml) * N_CLS;     // row ml+16   (mt=1)

    auto ld_gt = [&](int s, int4 (&d)[4]) {
        const int k = s * 32 + qoff;                          // multiple of 8
        if (k < N_CLS) {                                      // chunk fully valid or fully pad
            d[0] = *(const int4*)(g0 + k);
            d[1] = *(const int4*)(g0 + k + 4);
            d[2] = *(const int4*)(g1 + k);
            d[3] = *(const int4*)(g1 + k + 4);
        } else {
            d[0] = d[1] = d[2] = d[3] = make_int4(0, 0, 0, 0);
        }
    };

    // Bfrag[s][w][nt][lane][8]: s-stride 8192, nt-stride 512 elems
    const ushort* bb = Bfrag + ((size_t)w * 4 * 64 + lane) * 8;
    auto ld_B = [&](int s, bf16x8 (&b)[4]) {
        const ushort* p = bb + (size_t)s * 8192;
        b[0] = *(const bf16x8*)(p);
        b[1] = *(const bf16x8*)(p + 512);
        b[2] = *(const bf16x8*)(p + 1024);
        b[3] = *(const bf16x8*)(p + 1536);
    };

    int   rci0 = 0, rci1 = 0;
    float t2 = 0.f;

    auto convert = [&](int s, const int4 (&d)[4], bf16x8 (&a)[2]) {
        const int k = s * 32 + qoff;
        float4 c0 = *(const float4*)&csqS[k];       // zero-padded -> always in-bounds
        float4 c1 = *(const float4*)&csqS[k + 4];
        int v0[8] = {d[0].x, d[0].y, d[0].z, d[0].w, d[1].x, d[1].y, d[1].z, d[1].w};
        int v1[8] = {d[2].x, d[2].y, d[2].z, d[2].w, d[3].x, d[3].y, d[3].z, d[3].w};
        union { uint32_t u[4]; bf16x8 v; } p0, p1;
        #pragma unroll
        for (int j = 0; j < 4; j++) {               // v in {0,1}: pack 2x bf16(1.0)
            p0.u[j] = (uint32_t)(v0[2*j] + (v0[2*j+1] << 16)) * 0x3F80u;
            p1.u[j] = (uint32_t)(v1[2*j] + (v1[2*j+1] << 16)) * 0x3F80u;
        }
        a[0] = p0.v;
        a[1] = p1.v;
        float cs[8] = {c0.x, c0.y, c0.z, c0.w, c1.x, c1.y, c1.z, c1.w};
        #pragma unroll
        for (int j = 0; j < 8; j++) {
            rci0 += v0[j];
            rci1 += v1[j];
            t2   += cs[j] * (float)(v0[j] + v1[j]);
        }
    };

    auto domfma = [&](const bf16x8 (&a)[2], const bf16x8 (&b)[4]) {
        #pragma unroll
        for (int mt = 0; mt < 2; mt++)
            #pragma unroll
            for (int nt = 0; nt < 4; nt++)
                acc[mt][nt] = __builtin_amdgcn_mfma_f32_16x16x32_bf16(
                    a[mt], b[nt], acc[mt][nt], 0, 0, 0);
    };

    // ---- prologue: fill the 2-deep pipeline ----
    int4   gtP[4], gtQ[4];
    bf16x8 BfP[4], BfQ[4], AbfP[2], AbfQ[2];
    ld_gt(0, gtP);
    ld_gt(1, gtQ);
    ld_B(0, BfP);
    ld_B(1, BfQ);
    __syncthreads();                 // csqS visible (one-time; drains prologue loads, fine)
    convert(0, gtP, AbfP);

    // ---- steady state: no barriers, loads always in flight ----
    for (int s = 0; s < NSTG; s += 2) {
        const bool hn = (s + 2 < NSTG);
        // even stage s
        if (hn) ld_gt(s + 2, gtP);           // issue EARLY (oldest-first for vmcnt)
        domfma(AbfP, BfP);                   // waits only B(s); gt stays in flight
        convert(s + 1, gtQ, AbfQ);           // waits gt(s+1); B(s+1), gt(s+2) in flight
        if (hn) ld_B(s + 2, BfP);
        // odd stage s+1
        if (hn) ld_gt(s + 3, gtQ);
        domfma(AbfQ, BfQ);
        if (hn) convert(s + 2, gtP, AbfP);
        if (hn) ld_B(s + 3, BfQ);
    }

    // ---- reductions (register/shuffle only) ----
    float rc0 = (float)rci0, rc1 = (float)rci1;
    rc0 += __shfl_xor(rc0, 16); rc0 += __shfl_xor(rc0, 32);   // sum over quads -> rowcnt[ml], [ml+16]
    rc1 += __shfl_xor(rc1, 16); rc1 += __shfl_xor(rc1, 32);
    #pragma unroll
    for (int off = 32; off > 0; off >>= 1) t2 += __shfl_xor(t2, off);  // wave total (= block t2)

    // ---- epilogue: read features once, fold all terms ----
    float part = 0.f;
    #pragma unroll
    for (int mt = 0; mt < 2; mt++) {
        #pragma unroll
        for (int nt = 0; nt < 4; nt++) {
            const int n = w * 64 + nt * 16 + ml;
            #pragma unroll
            for (int reg = 0; reg < 4; reg++) {
                const int ri = mt * 16 + quad * 4 + reg;
                const float rowcnt = __shfl(mt == 0 ? rc0 : rc1, quad * 4 + reg);
                const float f = features[(size_t)(m0 + ri) * FEAT + n];
                part += f * (rowcnt * f - 2.f * acc[mt][nt][reg]);
            }
        }
    }
    #pragma unroll
    for (int off = 32; off > 0; off >>= 1) part += __shfl_down(part, off);
    if (lane == 0) blockred[w] = part + (w == 0 ? t2 : 0.f);
    __syncthreads();
    if (tid == 0)
        atomicAdd(out, (blockred[0] + blockred[1] + blockred[2] + blockred[3]) *
                           (1.f / (float)N_ROWS));
}

extern "C" void kernel_launch(void* const* d_in, const int* in_sizes, int n_in,
                              void* d_out, int out_size, void* d_ws, size_t ws_size,
                              hipStream_t stream) {
    const int*   gt       = (const int*)d_in[0];
    const float* features = (const float*)d_in[1];
    const float* centers  = (const float*)d_in[2];
    float*       out      = (float*)d_out;

    ushort* Bfrag = (ushort*)d_ws;                                    // 256*1024*2 = 512 KB
    float*  csq   = (float*)((char*)d_ws + (size_t)FEAT * KPAD * 2);  // 4 KB

    prep_kernel<<<KPAD, 256, 0, stream>>>(centers, Bfrag, csq, out);
    main_kernel<<<N_ROWS / MT, 256, 0, stream>>>(gt, features, Bfrag, csq, out);
}

// Round 7
// 432.709 us; speedup vs baseline: 1.1094x; 1.1094x over previous
//
#include <hip/hip_runtime.h>
#include <stdint.h>

#define N_ROWS 65536
#define N_CLS  1000
#define KPAD   1024
#define FEAT   256
#define MT     64            // rows per block in GEMM kernels
#define NSTG   32            // k-stages of 32
#define NIT    16            // fallback: k-iterations of 64

typedef short bf16x8 __attribute__((ext_vector_type(8)));
typedef float f32x4  __attribute__((ext_vector_type(4)));

__device__ __forceinline__ ushort f32_to_bf16_rne(float f) {
    union { float f; uint32_t u; } x; x.f = f;
    uint32_t u = x.u + 0x7FFFu + ((x.u >> 16) & 1u);
    return (ushort)(u >> 16);
}

// Prep: centers -> bf16 in MFMA B-fragment order
//   Bfrag[s][w][nt][lane][j]  (k = s*32+quad*8+j, lane=quad*16+ml, n=w*64+nt*16+ml)
// and csq[c] = ||centers[c]||^2 (zero-padded to KPAD); zero d_out.
__global__ __launch_bounds__(256) void prep_kernel(const float* __restrict__ centers,
                                                   ushort* __restrict__ Bfrag,
                                                   float* __restrict__ csq,
                                                   float* __restrict__ out) {
    const int c = blockIdx.x;     // k index 0..1023
    const int n = threadIdx.x;    // n index 0..255
    float v = 0.f;
    if (c < N_CLS) v = centers[(size_t)c * FEAT + n];

    const int s    = c >> 5;
    const int quad = (c >> 3) & 3;
    const int j    = c & 7;
    const int w    = n >> 6;
    const int nt   = (n >> 4) & 3;
    const int ml   = n & 15;
    const int lane = quad * 16 + ml;
    const size_t idx = (((size_t)(s * 4 + w) * 4 + nt) * 64 + lane) * 8 + j;
    Bfrag[idx] = f32_to_bf16_rne(v);

    float sq = v * v;
    #pragma unroll
    for (int off = 32; off > 0; off >>= 1) sq += __shfl_down(sq, off);
    __shared__ float red[4];
    if ((threadIdx.x & 63) == 0) red[threadIdx.x >> 6] = sq;
    __syncthreads();
    if (threadIdx.x == 0) {
        csq[c] = red[0] + red[1] + red[2] + red[3];
        if (c == 0) out[0] = 0.f;
    }
}

// ======================= two-pass path (needs 9.44 MB ws) =======================

// Pass 1: pure-streaming compress. One wave per row slice (8 rows/wave).
// Lane l reads cols {j*256 + l*4 .. +3} (int4, unit-stride across lanes ->
// coalesced 1 KB bursts). Packs 16 bits/lane: ushort[l] bit (j*4+i) <-> class
// j*256 + l*4 + i. Also rowcnt[row] (popcount) and t2row[row] = sum(mask*csq).
__global__ __launch_bounds__(256) void compress_kernel(const int* __restrict__ gt,
                                                       const float* __restrict__ csq,
                                                       ushort* __restrict__ bitmask,
                                                       float* __restrict__ rowcnt,
                                                       float* __restrict__ t2row) {
    __shared__ float csqS[KPAD];
    const int tid  = threadIdx.x;
    *(float4*)&csqS[tid * 4] = *(const float4*)&csq[tid * 4];
    __syncthreads();
    const int lane = tid & 63;
    const int wid  = blockIdx.x * 4 + (tid >> 6);    // 0..8191

    float4 cs[4];
    #pragma unroll
    for (int j = 0; j < 4; j++) cs[j] = *(const float4*)&csqS[j * 256 + lane * 4];
    const bool v3 = (768 + lane * 4) < N_CLS;        // j=3 validity (lane <= 57)

    auto ldrow = [&](int row, int4 (&d)[4]) {
        const int* g = gt + (size_t)row * N_CLS + lane * 4;
        d[0] = *(const int4*)(g);
        d[1] = *(const int4*)(g + 256);
        d[2] = *(const int4*)(g + 512);
        d[3] = v3 ? *(const int4*)(g + 768) : make_int4(0, 0, 0, 0);
    };
    auto proc = [&](int row, const int4 (&d)[4]) {
        uint32_t p =
              (uint32_t)d[0].x        | ((uint32_t)d[0].y << 1)  | ((uint32_t)d[0].z << 2)  | ((uint32_t)d[0].w << 3)
            | ((uint32_t)d[1].x << 4) | ((uint32_t)d[1].y << 5)  | ((uint32_t)d[1].z << 6)  | ((uint32_t)d[1].w << 7)
            | ((uint32_t)d[2].x << 8) | ((uint32_t)d[2].y << 9)  | ((uint32_t)d[2].z << 10) | ((uint32_t)d[2].w << 11)
            | ((uint32_t)d[3].x << 12)| ((uint32_t)d[3].y << 13) | ((uint32_t)d[3].z << 14) | ((uint32_t)d[3].w << 15);
        float t = (float)d[0].x * cs[0].x + (float)d[0].y * cs[0].y
                + (float)d[0].z * cs[0].z + (float)d[0].w * cs[0].w
                + (float)d[1].x * cs[1].x + (float)d[1].y * cs[1].y
                + (float)d[1].z * cs[1].z + (float)d[1].w * cs[1].w
                + (float)d[2].x * cs[2].x + (float)d[2].y * cs[2].y
                + (float)d[2].z * cs[2].z + (float)d[2].w * cs[2].w
                + (float)d[3].x * cs[3].x + (float)d[3].y * cs[3].y
                + (float)d[3].z * cs[3].z + (float)d[3].w * cs[3].w;
        int rc = __popc(p);
        #pragma unroll
        for (int off = 1; off < 64; off <<= 1) {
            rc += __shfl_xor(rc, off);
            t  += __shfl_xor(t, off);
        }
        bitmask[(size_t)row * 64 + lane] = (ushort)p;
        if (lane == 0) { rowcnt[row] = (float)rc; t2row[row] = t; }
    };

    // depth-2 pipelined over this wave's 8 rows (named buffers, static indexing)
    int4 dP[4], dQ[4];
    ldrow(wid, dP);
    ldrow(wid + 8192, dQ);
    #pragma unroll
    for (int rr = 0; rr < 8; rr += 2) {
        if (rr + 2 < 8) { proc(wid + rr * 8192, dP); ldrow(wid + (rr + 2) * 8192, dP); }
        else              proc(wid + rr * 8192, dP);
        if (rr + 3 < 8) { proc(wid + (rr + 1) * 8192, dQ); ldrow(wid + (rr + 3) * 8192, dQ); }
        else              proc(wid + (rr + 1) * 8192, dQ);
    }
}

// Pass 2: GEMM from bitmask. Bitmask rows staged once in LDS (33-dword pitch).
// Per stage each thread expands 8 A-bits/mt from one u32 to bf16 {0,1}; B from
// the L2-resident fragment table (1 KB bursts, depth-2). No barriers in loop.
__global__ __launch_bounds__(256, 3) void main2_kernel(const ushort* __restrict__ bitmask,
                                                       const float* __restrict__ features,
                                                       const ushort* __restrict__ Bfrag,
                                                       const float* __restrict__ rowcnt,
                                                       const float* __restrict__ t2row,
                                                       float* __restrict__ out) {
    __shared__ uint32_t bmS[MT * 33];    // 8448 B
    __shared__ float    rcS[MT], t2S[MT], blockred[4];

    const int tid  = threadIdx.x;
    const int lane = tid & 63;
    const int w    = tid >> 6;
    const int ml   = lane & 15;
    const int quad = lane >> 4;
    const int m0   = blockIdx.x * MT;

    const uint32_t* bm = (const uint32_t*)bitmask + (size_t)m0 * 32;
    #pragma unroll
    for (int i = 0; i < 8; i++) {
        int idx = i * 256 + tid;
        bmS[(idx >> 5) * 33 + (idx & 31)] = bm[idx];
    }
    if (tid < MT) rcS[tid] = rowcnt[m0 + tid];
    else if (tid < 2 * MT) t2S[tid - MT] = t2row[m0 + tid - MT];
    __syncthreads();

    f32x4 acc[4][4];
    #pragma unroll
    for (int i = 0; i < 4; i++)
        #pragma unroll
        for (int j = 0; j < 4; j++)
            #pragma unroll
            for (int k = 0; k < 4; k++) acc[i][j][k] = 0.f;

    const ushort* bb = Bfrag + ((size_t)w * 4 * 64 + lane) * 8;
    auto ld_B = [&](int s, bf16x8 (&b)[4]) {
        const ushort* p = bb + (size_t)s * 8192;
        b[0] = *(const bf16x8*)(p);
        b[1] = *(const bf16x8*)(p + 512);
        b[2] = *(const bf16x8*)(p + 1024);
        b[3] = *(const bf16x8*)(p + 1536);
    };

    auto dostage = [&](int s, const bf16x8 (&b)[4]) {
        const int dw = (s & 7) * 4 + quad;
        const int sb = (s >> 3) * 4;
        #pragma unroll
        for (int mt = 0; mt < 4; mt++) {
            const uint32_t W = bmS[(mt * 16 + ml) * 33 + dw];
            union { uint32_t u[4]; bf16x8 v; } a;
            #pragma unroll
            for (int p = 0; p < 4; p++) {
                const int b0 = (p < 2) ? (sb + 2 * p) : (16 + sb + 2 * (p - 2));
                a.u[p] = ((W >> b0) & 1u) * 0x3F80u
                       | ((W >> (b0 + 1)) & 1u) * 0x3F800000u;
            }
            #pragma unroll
            for (int nt = 0; nt < 4; nt++)
                acc[mt][nt] = __builtin_amdgcn_mfma_f32_16x16x32_bf16(
                    a.v, b[nt], acc[mt][nt], 0, 0, 0);
        }
    };

    bf16x8 BfP[4], BfQ[4];
    ld_B(0, BfP);
    ld_B(1, BfQ);
    for (int s = 0; s < NSTG; s += 2) {
        dostage(s, BfP);
        if (s + 2 < NSTG) ld_B(s + 2, BfP);
        dostage(s + 1, BfQ);
        if (s + 3 < NSTG) ld_B(s + 3, BfQ);
    }

    float part = 0.f;
    #pragma unroll
    for (int mt = 0; mt < 4; mt++) {
        #pragma unroll
        for (int nt = 0; nt < 4; nt++) {
            const int n = w * 64 + nt * 16 + ml;
            #pragma unroll
            for (int reg = 0; reg < 4; reg++) {
                const int ri = mt * 16 + quad * 4 + reg;
                const float f = features[(size_t)(m0 + ri) * FEAT + n];
                part += f * (rcS[ri] * f - 2.f * acc[mt][nt][reg]) + t2S[ri] * (1.f / 256.f);
            }
        }
    }
    #pragma unroll
    for (int off = 32; off > 0; off >>= 1) part += __shfl_down(part, off);
    if (lane == 0) blockred[w] = part;
    __syncthreads();
    if (tid == 0)
        atomicAdd(out, (blockred[0] + blockred[1] + blockred[2] + blockred[3]) *
                           (1.f / (float)N_ROWS));
}

// ============== fallback path (R4 kernel, verified: 516 KB ws) ==============
__global__ __launch_bounds__(256, 3) void fused_kernel(const int* __restrict__ gt,
                                                       const float* __restrict__ features,
                                                       const ushort* __restrict__ Bfrag,
                                                       const float* __restrict__ csq,
                                                       float* __restrict__ out) {
    __shared__ ushort As[2 * 2 * 4 * 64 * 8];
    __shared__ float  csqS[KPAD];
    __shared__ float  rcS[256], t2S[256], rowcnt[MT], t2row[MT], blockred[4];

    const int tid  = threadIdx.x;
    const int m0   = blockIdx.x * MT;
    const int r    = tid >> 2;
    const int kc   = tid & 3;
    const int lane = tid & 63;
    const int w    = tid >> 6;
    const int ml   = lane & 15;
    const int quad = lane >> 4;

    f32x4 acc[4][4];
    #pragma unroll
    for (int i = 0; i < 4; i++)
        #pragma unroll
        for (int j = 0; j < 4; j++)
            #pragma unroll
            for (int k = 0; k < 4; k++) acc[i][j][k] = 0.f;

    int   rci = 0;
    float t2  = 0.f;
    const int* gtrow = gt + (size_t)(m0 + r) * N_CLS;

    const int mt_w = r >> 4, ml_w = r & 15;
    const int ks_w = kc >> 1, qb = (kc & 1) * 2;
    const int xw   = (ml_w >> 3) | (ks_w << 1) | ((kc & 1) << 2);
    const int slot0 = (((ks_w * 4 + mt_w) * 64) + (qb * 16 + ml_w)) ^ xw;
    const int slot1 = (((ks_w * 4 + mt_w) * 64) + ((qb + 1) * 16 + ml_w)) ^ xw;
    ushort* const wptr0 = As + slot0 * 8;
    ushort* const wptr1 = As + slot1 * 8;

    const int xr0 = ((lane >> 3) & 1) | (((lane >> 5) & 1) << 2);
    const int lx0 = (lane ^ xr0) * 8;
    const int lx1 = (lane ^ (xr0 | 2)) * 8;

    auto load_gt = [&](int it, int (&vv)[16]) {
        const int kb = it * 64 + kc * 16;
        if (kb + 16 <= N_CLS) {
            const int4* p = (const int4*)(gtrow + kb);
            int4 a0 = p[0], a1 = p[1], a2 = p[2], a3 = p[3];
            vv[0]=a0.x;  vv[1]=a0.y;  vv[2]=a0.z;  vv[3]=a0.w;
            vv[4]=a1.x;  vv[5]=a1.y;  vv[6]=a1.z;  vv[7]=a1.w;
            vv[8]=a2.x;  vv[9]=a2.y;  vv[10]=a2.z; vv[11]=a2.w;
            vv[12]=a3.x; vv[13]=a3.y; vv[14]=a3.z; vv[15]=a3.w;
        } else {
            #pragma unroll
            for (int j = 0; j < 16; j++) {
                int k = kb + j;
                vv[j] = (k < N_CLS) ? gtrow[k] : 0;
            }
        }
    };

    auto convert_store = [&](int buf, int it, const int (&vv)[16]) {
        const int kb = it * 64 + kc * 16;
        const float4* cp = (const float4*)&csqS[kb];
        float4 q0 = cp[0], q1 = cp[1], q2 = cp[2], q3 = cp[3];
        float cs[16] = {q0.x,q0.y,q0.z,q0.w, q1.x,q1.y,q1.z,q1.w,
                        q2.x,q2.y,q2.z,q2.w, q3.x,q3.y,q3.z,q3.w};
        uint32_t u[8];
        #pragma unroll
        for (int j = 0; j < 8; j++)
            u[j] = (uint32_t)(vv[2*j] + (vv[2*j+1] << 16)) * 0x3F80u;
        #pragma unroll
        for (int j = 0; j < 16; j++) { rci += vv[j]; t2 += (float)vv[j] * cs[j]; }
        uint4* d0 = (uint4*)(wptr0 + buf * 4096);
        uint4* d1 = (uint4*)(wptr1 + buf * 4096);
        *d0 = make_uint4(u[0], u[1], u[2], u[3]);
        *d1 = make_uint4(u[4], u[5], u[6], u[7]);
    };

    const ushort* bbase = Bfrag + ((size_t)w * 4) * 64 * 8 + (size_t)lane * 8;
    auto mfma_iter = [&](int buf, int it) {
        bf16x8 b0[4], b1[4];
        const ushort* p0 = bbase + (size_t)(it * 2 + 0) * (4 * 4 * 64 * 8);
        const ushort* p1 = bbase + (size_t)(it * 2 + 1) * (4 * 4 * 64 * 8);
        #pragma unroll
        for (int nt = 0; nt < 4; ++nt) b0[nt] = *(const bf16x8*)(p0 + nt * 64 * 8);
        #pragma unroll
        for (int nt = 0; nt < 4; ++nt) b1[nt] = *(const bf16x8*)(p1 + nt * 64 * 8);
        #pragma unroll
        for (int ks = 0; ks < 2; ++ks) {
            const int lx = ks ? lx1 : lx0;
            bf16x8 af[4];
            #pragma unroll
            for (int mt = 0; mt < 4; mt++)
                af[mt] = *(const bf16x8*)(As + buf * 4096 + (ks * 4 + mt) * 512 + lx);
            #pragma unroll
            for (int mt = 0; mt < 4; mt++)
                #pragma unroll
                for (int nt = 0; nt < 4; nt++)
                    acc[mt][nt] = __builtin_amdgcn_mfma_f32_16x16x32_bf16(
                        af[mt], ks ? b1[nt] : b0[nt], acc[mt][nt], 0, 0, 0);
        }
    };

    int gtA[16], gtB[16];
    {
        *(float4*)&csqS[tid * 4] = *(const float4*)&csq[tid * 4];
        load_gt(0, gtA);
        __syncthreads();
        convert_store(0, 0, gtA);
        load_gt(1, gtA);
        __syncthreads();
    }
    for (int it = 0; it < NIT; it += 2) {
        if (it + 2 < NIT) load_gt(it + 2, gtB);
        mfma_iter(0, it);
        if (it + 1 < NIT) convert_store(1, it + 1, gtA);
        __syncthreads();
        if (it + 3 < NIT) load_gt(it + 3, gtA);
        mfma_iter(1, it + 1);
        if (it + 2 < NIT) convert_store(0, it + 2, gtB);
        __syncthreads();
    }

    rcS[tid] = (float)rci;
    t2S[tid] = t2;
    __syncthreads();
    if (tid < MT) {
        rowcnt[tid] = rcS[tid*4] + rcS[tid*4+1] + rcS[tid*4+2] + rcS[tid*4+3];
        t2row[tid]  = t2S[tid*4] + t2S[tid*4+1] + t2S[tid*4+2] + t2S[tid*4+3];
    }
    __syncthreads();

    float part = 0.f;
    #pragma unroll
    for (int mt = 0; mt < 4; mt++) {
        #pragma unroll
        for (int nt = 0; nt < 4; nt++) {
            const int n = w * 64 + nt * 16 + ml;
            #pragma unroll
            for (int reg = 0; reg < 4; reg++) {
                const int ri = mt * 16 + quad * 4 + reg;
                const float f = features[(size_t)(m0 + ri) * FEAT + n];
                part += f * (rowcnt[ri] * f - 2.f * acc[mt][nt][reg]) + t2row[ri] * (1.f / 256.f);
            }
        }
    }
    #pragma unroll
    for (int off = 32; off > 0; off >>= 1) part += __shfl_down(part, off);
    if (lane == 0) blockred[w] = part;
    __syncthreads();
    if (tid == 0)
        atomicAdd(out, (blockred[0] + blockred[1] + blockred[2] + blockred[3]) *
                           (1.f / (float)N_ROWS));
}

extern "C" void kernel_launch(void* const* d_in, const int* in_sizes, int n_in,
                              void* d_out, int out_size, void* d_ws, size_t ws_size,
                              hipStream_t stream) {
    const int*   gt       = (const int*)d_in[0];
    const float* features = (const float*)d_in[1];
    const float* centers  = (const float*)d_in[2];
    float*       out      = (float*)d_out;

    char* ws = (char*)d_ws;
    ushort* Bfrag = (ushort*)(ws);                    // 524288 B
    float*  csq   = (float*)(ws + 524288);            // 4096 B

    prep_kernel<<<KPAD, 256, 0, stream>>>(centers, Bfrag, csq, out);

    const size_t REQ = 524288u + 4096u + 262144u + 262144u + 8388608u;  // 9441280
    if (ws_size >= REQ) {
        float*  rowcnt  = (float*)(ws + 528384);
        float*  t2row   = (float*)(ws + 790528);
        ushort* bitmask = (ushort*)(ws + 1052672);
        compress_kernel<<<2048, 256, 0, stream>>>(gt, csq, bitmask, rowcnt, t2row);
        main2_kernel<<<N_ROWS / MT, 256, 0, stream>>>(bitmask, features, Bfrag,
                                                      rowcnt, t2row, out);
    } else {
        fused_kernel<<<N_ROWS / MT, 256, 0, stream>>>(gt, features, Bfrag, csq, out);
    }
}